// Round 11
// baseline (638.225 us; speedup 1.0000x reference)
//
#include <hip/hip_runtime.h>
#include <math.h>

typedef unsigned short ushort_t;

#define B_SZ 8
#define LSEQ 512
#define DM 768
#define DI 1536
#define DSTATE 16
#define DTRANK 48
#define M_ROWS (B_SZ * LSEQ)   // 4096

#define FLAG_SP   1
#define FLAG_CONV 2
#define FLAG_FUSE 4
#define FLAG_PB16 8

#define SEG 16
#define SL  32

using short8v = __attribute__((ext_vector_type(8))) short;
using float4v = __attribute__((ext_vector_type(4))) float;

#define AS1(p) ((const __attribute__((address_space(1))) void*)(p))
#define AS3(p) ((__attribute__((address_space(3))) void*)(p))

__device__ __forceinline__ float us2f(ushort_t u) {
    union { unsigned int i; float f; } cv; cv.i = ((unsigned int)u) << 16; return cv.f;
}
__device__ __forceinline__ ushort_t f2bs(float f) {
    union { float f; unsigned int u; } cv; cv.f = f;
    unsigned int r = cv.u + 0x7FFFu + ((cv.u >> 16) & 1u);   // RNE
    return (ushort_t)(r >> 16);
}

// ---------------------------------------------------------------------------
// MFMA GEMM with direct global->LDS (width=16) staging.
// C[4096][N] = A[4096][lda](bf16) @ Wt^T (+b1+b2); Wt is [N][K] bf16.
// Split-K partials: fp32 (default) or bf16 (FLAG_PB16) into Part.
// ---------------------------------------------------------------------------
template <int TM, int TN>
__global__ __launch_bounds__(256) void gemm_k(
    const ushort_t* __restrict__ A, int lda,
    const ushort_t* __restrict__ Wt,
    const float* __restrict__ b1, const float* __restrict__ b2,
    float* __restrict__ Cf, ushort_t* __restrict__ Cb, int ldc,
    int N, int K, int flags, int ktiles_per_z, void* __restrict__ Part,
    const ushort_t* __restrict__ zpage, const ushort_t* __restrict__ Gm)
{
    constexpr int MF = TM / 32;
    constexpr int NF = TN / 32;
    constexpr int AI = TM / 32;      // A 16B-issues per wave
    constexpr int BI = TN / 32;
    __shared__ short Alds[8 * TM * 8];
    __shared__ short Blds[8 * TN * 8];

    const int tid  = threadIdx.x;
    const int wave = tid >> 6;
    const int lane = tid & 63;
    const int l16  = lane & 15;
    const int quad = lane >> 4;
    const int bm   = blockIdx.x * TM;
    const int bn   = blockIdx.y * TN;
    const int wm   = (wave & 1) * (TM / 2);
    const int wn   = (wave >> 1) * (TN / 2);

    float4v acc[MF][NF];
    #pragma unroll
    for (int i = 0; i < MF; i++)
        #pragma unroll
        for (int j = 0; j < NF; j++)
            acc[i][j] = (float4v){0.f, 0.f, 0.f, 0.f};

    const int nkt = (K + 63) >> 6;
    const int kt0 = blockIdx.z * ktiles_per_z;
    const int kt1 = min(nkt, kt0 + ktiles_per_z);
    for (int kt = kt0; kt < kt1; ++kt) {
        const int k0 = kt << 6;
        int koff = k0, sh = 0;
        if (flags & FLAG_CONV) {
            const int seg = kt / 12;
            koff = (kt - seg * 12) << 6;
            sh = (seg < 7) ? (seg - 3) : 0;
        }
        // A staging
        #pragma unroll
        for (int i = 0; i < AI; i++) {
            const int j = wave * AI + i;
            const int slot = j * 64 + lane;
            const int c = slot / TM, r = slot % TM;
            const int mg = bm + r;
            const ushort_t* gp = zpage;
            if (flags & FLAG_CONV) {
                const int ls = (mg & 511) + sh;
                if (ls >= 0 && ls < LSEQ)
                    gp = A + (size_t)((mg >> 9) * LSEQ + ls) * lda + koff + c * 8;
            } else {
                if (k0 + c * 8 < K)
                    gp = A + (size_t)mg * lda + k0 + c * 8;
            }
            __builtin_amdgcn_global_load_lds(AS1(gp), AS3(Alds + j * 512), 16, 0, 0);
        }
        // B staging
        #pragma unroll
        for (int i = 0; i < BI; i++) {
            const int j = wave * BI + i;
            const int slot = j * 64 + lane;
            const int c = slot / TN, r = slot % TN;
            const int ng = bn + r;
            const ushort_t* gp = zpage;
            if (ng < N && (k0 + c * 8) < K)
                gp = Wt + (size_t)ng * K + k0 + c * 8;
            __builtin_amdgcn_global_load_lds(AS1(gp), AS3(Blds + j * 512), 16, 0, 0);
        }
        __syncthreads();

        short8v a0[MF], a1[MF], b0[NF], b1v[NF];
        #pragma unroll
        for (int mi = 0; mi < MF; mi++) {
            const int ar = wm + mi * 16 + l16;
            a0[mi] = *(const short8v*)(Alds + ((size_t)quad * TM + ar) * 8);
            a1[mi] = *(const short8v*)(Alds + ((size_t)(4 + quad) * TM + ar) * 8);
        }
        #pragma unroll
        for (int ni = 0; ni < NF; ni++) {
            const int br = wn + ni * 16 + l16;
            b0[ni] = *(const short8v*)(Blds + ((size_t)quad * TN + br) * 8);
            b1v[ni] = *(const short8v*)(Blds + ((size_t)(4 + quad) * TN + br) * 8);
        }
        #pragma unroll
        for (int mi = 0; mi < MF; mi++)
            #pragma unroll
            for (int ni = 0; ni < NF; ni++) {
                acc[mi][ni] = __builtin_amdgcn_mfma_f32_16x16x32_bf16(
                    a0[mi], b0[ni], acc[mi][ni], 0, 0, 0);
                acc[mi][ni] = __builtin_amdgcn_mfma_f32_16x16x32_bf16(
                    a1[mi], b1v[ni], acc[mi][ni], 0, 0, 0);
            }
        __syncthreads();
    }

    if (Part) {
        const size_t zoff = (size_t)blockIdx.z * M_ROWS * N;
        #pragma unroll
        for (int ni = 0; ni < NF; ni++) {
            const int col = bn + wn + ni * 16 + l16;
            if (col >= N) continue;
            #pragma unroll
            for (int mi = 0; mi < MF; mi++) {
                const int row0 = bm + wm + mi * 16 + quad * 4;
                #pragma unroll
                for (int r = 0; r < 4; r++) {
                    const size_t idx = zoff + (size_t)(row0 + r) * N + col;
                    if (flags & FLAG_PB16)
                        ((ushort_t*)Part)[idx] = f2bs(acc[mi][ni][r]);
                    else
                        ((float*)Part)[idx] = acc[mi][ni][r];
                }
            }
        }
        return;
    }

    #pragma unroll
    for (int ni = 0; ni < NF; ni++) {
        const int col = bn + wn + ni * 16 + l16;
        if (col >= N) continue;
        const float bias = (b1 ? b1[col] : 0.f) + (b2 ? b2[col] : 0.f);
        #pragma unroll
        for (int mi = 0; mi < MF; mi++) {
            const int row0 = bm + wm + mi * 16 + quad * 4;
            #pragma unroll
            for (int r = 0; r < 4; r++) {
                float v = acc[mi][ni][r] + bias;
                const int row = row0 + r;
                if (flags & FLAG_FUSE) {
                    const float g = 1.f / (1.f + __expf(-v));
                    const float xg = us2f(Gm[(size_t)row * (2 * DM) + col]);
                    const float xm = us2f(Gm[(size_t)row * (2 * DM) + DM + col]);
                    Cb[(size_t)row * ldc + col] = f2bs(g * xg + (1.f - g) * xm);
                    continue;
                }
                if (flags & FLAG_SP) v = (v > 20.f) ? v : log1pf(__expf(v));
                const size_t idx = (size_t)row * ldc + col;
                if (Cf) Cf[idx] = v;
                else    Cb[idx] = f2bs(v);
            }
        }
    }
}

// reduce fp32 split-K partials + bias (+softplus)
__global__ void combine_k(const float* __restrict__ Part, int nsplit, int N,
                          const float* __restrict__ b1, const float* __restrict__ b2,
                          float* __restrict__ Cf, ushort_t* __restrict__ Cb,
                          int ldc, int flags)
{
    int t = blockIdx.x * 256 + threadIdx.x;
    if (t >= M_ROWS * N) return;
    const int row = t / N, col = t - row * N;
    float v = 0.f;
    for (int s = 0; s < nsplit; s++) v += Part[(size_t)s * M_ROWS * N + t];
    if (b1) v += b1[col];
    if (b2) v += b2[col];
    if (flags & FLAG_SP) v = (v > 20.f) ? v : log1pf(__expf(v));
    const size_t idx = (size_t)row * ldc + col;
    if (Cf) Cf[idx] = v;
    else    Cb[idx] = f2bs(v);
}

// reduce bf16 split-K partials + bias; optional fused sigmoid-blend (Gm)
__global__ void combineb_k(const ushort_t* __restrict__ Part, int nsplit, int N,
                           const float* __restrict__ b1, const float* __restrict__ b2,
                           float* __restrict__ Cf, ushort_t* __restrict__ Cb,
                           int ldc, int flags, const ushort_t* __restrict__ Gm)
{
    int t = blockIdx.x * 256 + threadIdx.x;
    if (t >= M_ROWS * N) return;
    const int row = t / N, col = t - row * N;
    float v = 0.f;
    for (int s = 0; s < nsplit; s++) v += us2f(Part[(size_t)s * M_ROWS * N + t]);
    if (b1) v += b1[col];
    if (b2) v += b2[col];
    if (flags & FLAG_FUSE) {
        const float g = 1.f / (1.f + __expf(-v));
        const float xg = us2f(Gm[(size_t)row * (2 * DM) + col]);
        const float xm = us2f(Gm[(size_t)row * (2 * DM) + DM + col]);
        Cb[(size_t)row * ldc + col] = f2bs(g * xg + (1.f - g) * xm);
        return;
    }
    if (flags & FLAG_SP) v = (v > 20.f) ? v : log1pf(__expf(v));
    const size_t idx = (size_t)row * ldc + col;
    if (Cf) Cf[idx] = v;
    else    Cb[idx] = f2bs(v);
}

// adj = sigmoid(nv1 @ nv2) * (1 - eye)  -> fp32
__global__ void adj_k(const float* __restrict__ nv1, const float* __restrict__ nv2,
                      float* __restrict__ out)
{
    int t = blockIdx.x * 256 + threadIdx.x;
    if (t >= 64 * 64) return;
    int i = t >> 6, j = t & 63;
    float s = 0.f;
    #pragma unroll
    for (int k = 0; k < 16; k++) s += nv1[i * 16 + k] * nv2[k * 64 + j];
    out[t] = (i == j) ? 0.f : 1.f / (1.f + __expf(-s));
}

// LayerNorm over last dim (768)
__global__ __launch_bounds__(256) void ln_k(
    const float* __restrict__ xin, const float* __restrict__ addf,
    const float* __restrict__ w, const float* __restrict__ bparam,
    float* __restrict__ outf, ushort_t* __restrict__ outb)
{
    const int r = blockIdx.x;
    const int tid = threadIdx.x;
    const size_t base = (size_t)r * DM;
    float v[3];
    float s = 0.f, ss = 0.f;
    #pragma unroll
    for (int j = 0; j < 3; j++) {
        const int c = tid + 256 * j;
        float vv = xin[base + c];
        if (addf) vv += addf[base + c];
        v[j] = vv; s += vv; ss += vv * vv;
    }
    #pragma unroll
    for (int o = 32; o > 0; o >>= 1) { s += __shfl_down(s, o); ss += __shfl_down(ss, o); }
    __shared__ float sw[4], ssw[4];
    __shared__ float mu_s, rs_s;
    const int wid = tid >> 6;
    if ((tid & 63) == 0) { sw[wid] = s; ssw[wid] = ss; }
    __syncthreads();
    if (tid == 0) {
        float st = 0.f, sst = 0.f;
        #pragma unroll
        for (int i = 0; i < 4; i++) { st += sw[i]; sst += ssw[i]; }
        const float mu = st / (float)DM;
        const float var = sst / (float)DM - mu * mu;
        mu_s = mu; rs_s = rsqrtf(fmaxf(var, 0.f) + 1e-5f);
    }
    __syncthreads();
    const float mu = mu_s, rs = rs_s;
    #pragma unroll
    for (int j = 0; j < 3; j++) {
        const int c = tid + 256 * j;
        const float o = (v[j] - mu) * rs * w[c] + bparam[c];
        if (outf) outf[base + c] = o;
        if (outb) outb[base + c] = f2bs(o);
    }
}

// batched tiled transpose+cvt: 7 descriptors, flat tile index
struct TDesc { const float* in; ushort_t* out; int R, C, ldout, off, tile0; };
struct TPack { TDesc d[7]; };
__global__ void tcvt7_k(TPack p)
{
    __shared__ float tile[32][33];
    int di = 0;
    #pragma unroll
    for (int i = 1; i < 7; i++) if (blockIdx.x >= p.d[i].tile0) di = i;
    const TDesc dd = p.d[di];
    const int lt = blockIdx.x - dd.tile0;
    const int tilesX = (dd.C + 31) >> 5;
    const int c0 = (lt % tilesX) * 32, r0 = (lt / tilesX) * 32;
    const int tx = threadIdx.x, ty = threadIdx.y;   // (32, 8)
    #pragma unroll
    for (int j = 0; j < 4; j++) {
        const int rr = r0 + ty + j * 8;
        if (rr < dd.R && c0 + tx < dd.C)
            tile[ty + j * 8][tx] = dd.in[(size_t)rr * dd.C + c0 + tx];
    }
    __syncthreads();
    #pragma unroll
    for (int j = 0; j < 4; j++) {
        const int cc = c0 + ty + j * 8;
        const int kk = r0 + tx;
        if (cc < dd.C && kk < dd.R)
            dd.out[(size_t)cc * dd.ldout + dd.off + kk] = f2bs(tile[tx][ty + j * 8]);
    }
}

// wcat_t[768][6144]
__global__ void wcat_k(const float* __restrict__ cw, const float* __restrict__ gw,
                       ushort_t* __restrict__ out)
{
    int t = blockIdx.x * 256 + threadIdx.x;
    if (t >= DM * 8 * DM) return;
    const int o = t / (8 * DM);
    const int rr = t - o * 8 * DM;
    const int seg = rr / DM;
    const int i = rr - seg * DM;
    float v = (seg < 7) ? cw[(size_t)o * (DM * 7) + i * 7 + seg]
                        : gw[(size_t)i * DM + o];
    out[t] = f2bs(v);
}

// depthwise causal conv + bias + silu
__global__ void dwconv_k(const ushort_t* __restrict__ xz, const float* __restrict__ w,
                         const float* __restrict__ bcv, ushort_t* __restrict__ out)
{
    int t = blockIdx.x * 256 + threadIdx.x;
    if (t >= M_ROWS * DI) return;
    const int d = t % DI;
    const int bl = t / DI;
    const int l = bl & 511;
    const ushort_t* xp = xz + (size_t)bl * (2 * DI) + d;
    float s = bcv[d];
    #pragma unroll
    for (int k = 0; k < 4; k++) {
        const int ls = l + k - 3;
        if (ls >= 0) s += w[d * 4 + k] * us2f(xp[(ptrdiff_t)(k - 3) * (2 * DI)]);
    }
    out[t] = f2bs(s / (1.f + __expf(-s)));
}

// ---------------------------------------------------------------------------
// Segmented selective scan (unchanged)
// ---------------------------------------------------------------------------
__global__ __launch_bounds__(256) void scan_a_k(
    const float* __restrict__ dtb, const ushort_t* __restrict__ xmc,
    const ushort_t* __restrict__ xdbl, const float* __restrict__ A_log,
    ushort_t* __restrict__ Aseg, float* __restrict__ Bseg)
{
    __shared__ ushort_t B_s[SL][16];
    const int tid = threadIdx.x;
    const int d   = blockIdx.x * 256 + tid;
    const int b   = blockIdx.y;
    const int sg  = blockIdx.z;
    const int l0  = sg * SL;

    const ushort_t* dbp = xdbl + ((size_t)b * LSEQ + l0) * 80;
    #pragma unroll
    for (int e = 0; e < 2; e++) {
        const int idx = tid + e * 256;
        const int ll = idx >> 4, n = idx & 15;
        B_s[ll][n] = dbp[(size_t)ll * 80 + DTRANK + n];
    }

    float Ad[16], h[16], Ap[16];
    #pragma unroll
    for (int n = 0; n < 16; n++) {
        Ad[n] = -__expf(A_log[(size_t)d * DSTATE + n]);
        h[n] = 0.f; Ap[n] = 1.f;
    }
    const float*    dtp = dtb + ((size_t)b * LSEQ + l0) * DI + d;
    const ushort_t* xp  = xmc + ((size_t)b * LSEQ + l0) * DI + d;
    __syncthreads();

    for (int l = 0; l < SL; ++l) {
        const float dtv = dtp[(size_t)l * DI];
        const float dx  = dtv * us2f(xp[(size_t)l * DI]);
        #pragma unroll
        for (int n = 0; n < 16; n++) {
            const float a = __expf(dtv * Ad[n]);
            h[n] = a * h[n] + us2f(B_s[l][n]) * dx;
            Ap[n] *= a;
        }
    }
    #pragma unroll
    for (int n = 0; n < 16; n++) {
        const size_t o = ((size_t)(b * SEG + sg) * 16 + n) * DI + d;
        Aseg[o] = f2bs(Ap[n]);
        Bseg[o] = h[n];
    }
}

__global__ __launch_bounds__(256) void scan_b_k(
    const float* __restrict__ dtb, ushort_t* __restrict__ xmc,
    const ushort_t* __restrict__ xdbl, const ushort_t* __restrict__ xz,
    const float* __restrict__ A_log, const float* __restrict__ Dp,
    const ushort_t* __restrict__ Aseg, const float* __restrict__ Bseg)
{
    __shared__ ushort_t B_s[SL][16];
    __shared__ ushort_t C_s[SL][16];
    const int tid = threadIdx.x;
    const int d   = blockIdx.x * 256 + tid;
    const int b   = blockIdx.y;
    const int sg  = blockIdx.z;
    const int l0  = sg * SL;

    const ushort_t* dbp = xdbl + ((size_t)b * LSEQ + l0) * 80;
    #pragma unroll
    for (int e = 0; e < 2; e++) {
        const int idx = tid + e * 256;
        const int ll = idx >> 4, n = idx & 15;
        B_s[ll][n] = dbp[(size_t)ll * 80 + DTRANK + n];
        C_s[ll][n] = dbp[(size_t)ll * 80 + DTRANK + DSTATE + n];
    }

    float Ad[16], h[16];
    #pragma unroll
    for (int n = 0; n < 16; n++) {
        Ad[n] = -__expf(A_log[(size_t)d * DSTATE + n]);
        h[n] = 0.f;
    }
    for (int s = 0; s < sg; ++s) {
        #pragma unroll
        for (int n = 0; n < 16; n++) {
            const size_t o = ((size_t)(b * SEG + s) * 16 + n) * DI + d;
            h[n] = us2f(Aseg[o]) * h[n] + Bseg[o];
        }
    }
    const float Dd = Dp[d];
    const float*    dtp = dtb + ((size_t)b * LSEQ + l0) * DI + d;
    ushort_t*       xp  = xmc + ((size_t)b * LSEQ + l0) * DI + d;
    const ushort_t* zp  = xz  + ((size_t)b * LSEQ + l0) * (2 * DI) + DI + d;
    __syncthreads();

    for (int l = 0; l < SL; ++l) {
        const float dtv = dtp[(size_t)l * DI];
        const float xv  = us2f(xp[(size_t)l * DI]);
        const float dx  = dtv * xv;
        float p = 0.f;
        #pragma unroll
        for (int n = 0; n < 16; n++) {
            const float a = __expf(dtv * Ad[n]);
            h[n] = a * h[n] + us2f(B_s[l][n]) * dx;
            p += h[n] * us2f(C_s[l][n]);
        }
        const float zv = us2f(zp[(size_t)l * 2 * DI]);
        const float sz = zv / (1.f + __expf(-zv));
        xp[(size_t)l * DI] = f2bs((p + Dd * xv) * sz);
    }
}

extern "C" void kernel_launch(void* const* d_in, const int* in_sizes, int n_in,
                              void* d_out, int out_size, void* d_ws, size_t ws_size,
                              hipStream_t stream)
{
    const float* x        = (const float*)d_in[0];
    const float* nv1      = (const float*)d_in[1];
    const float* nv2      = (const float*)d_in[2];
    const float* n1w      = (const float*)d_in[3];
    const float* n1b      = (const float*)d_in[4];
    const float* n2w      = (const float*)d_in[5];
    const float* n2b      = (const float*)d_in[6];
    const float* gcn_w    = (const float*)d_in[7];
    const float* gcn_b    = (const float*)d_in[8];
    const float* conv_w   = (const float*)d_in[9];
    const float* conv_b   = (const float*)d_in[10];
    const float* ggw      = (const float*)d_in[11];
    const float* ggb      = (const float*)d_in[12];
    const float* gmw      = (const float*)d_in[13];
    const float* gmb      = (const float*)d_in[14];
    const float* ow       = (const float*)d_in[15];
    const float* ob       = (const float*)d_in[16];
    const float* m_in_w   = (const float*)d_in[17];
    const float* m_conv_w = (const float*)d_in[18];
    const float* m_conv_b = (const float*)d_in[19];
    const float* m_xproj_w= (const float*)d_in[20];
    const float* m_dt_w   = (const float*)d_in[21];
    const float* m_dt_b   = (const float*)d_in[22];
    const float* m_A_log  = (const float*)d_in[23];
    const float* m_D      = (const float*)d_in[24];
    const float* m_out_w  = (const float*)d_in[25];

    float* out_main = (float*)d_out;
    float* out_adj  = out_main + (size_t)M_ROWS * DM;

    // workspace layout (~98.1 MB incl. zero page)
    ushort_t* wsb = (ushort_t*)d_ws;
    ushort_t* xn_bf   = wsb;                       //  3,145,728
    ushort_t* xz_bf   = xn_bf   + 3145728;         // 12,582,912
    ushort_t* xmc_bf  = xz_bf   + 12582912;        //  6,291,456 (y in place)
    ushort_t* xdbl_bf = xmc_bf  + 6291456;         //    327,680
    ushort_t* gcnmam  = xdbl_bf + 327680;          //  6,291,456 [xgcn|xmamba]
    ushort_t* wcat_t  = gcnmam  + 6291456;         //  4,718,592
    ushort_t* in_w_t  = wcat_t  + 4718592;         //  2,359,296
    ushort_t* xproj_t = in_w_t  + 2359296;         //    122,880
    ushort_t* dtw_t   = xproj_t + 122880;          //     73,728
    ushort_t* outw_t  = dtw_t   + 73728;           //  1,179,648
    ushort_t* gates_t = outw_t  + 1179648;         //  1,179,648
    ushort_t* ow_t    = gates_t + 1179648;         //    589,824
    float*    dtb     = (float*)(ow_t + 589824);   //  6,291,456 fp32
    ushort_t* zpage   = (ushort_t*)(dtb + 6291456);//  256 B zeroed
    // aliases
    ushort_t* fused   = xz_bf + 3145728;           // xz dead after scan
    float*    outtmp  = dtb;                       // dtb dead after gate partials
    ushort_t* P1b     = xz_bf;                     // conv bf16 partials: 6x6.29M ush = xz+xmc region (exact, dead pre-in_proj)
    float*    P2      = (float*)wcat_t;            // xproj fp32 partials (wcat dead)
    ushort_t* P3b     = (ushort_t*)dtb;            // out_proj bf16 partials: 4x3.15M ush (dtb dead post-scan)
    ushort_t* P4b     = xmc_bf;                    // gate bf16 partials: 2x3.15M ush (xmc dead post-out_proj)
    ushort_t* Aseg    = xn_bf;                     // xn dead after in_proj
    float*    Bseg    = (float*)wcat_t;            // wcat+in_w dead after GEMMs

    const dim3 blk(256);
    const dim3 tblk(32, 8);

    hipMemsetAsync(zpage, 0, 256, stream);

    // ---- weight prep ----
    wcat_k<<<(DM * 8 * DM + 255) / 256, blk, 0, stream>>>(conv_w, gcn_w, wcat_t);
    TPack tp;
    int t0 = 0;
    auto fill = [&](int i, const float* in, ushort_t* out, int R, int C, int ldo, int off) {
        tp.d[i] = TDesc{in, out, R, C, ldo, off, t0};
        t0 += ((C + 31) / 32) * ((R + 31) / 32);
    };
    fill(0, m_in_w,    in_w_t,  768, 3072, 768, 0);
    fill(1, m_xproj_w, xproj_t, 1536, 80, 1536, 0);
    fill(2, m_dt_w,    dtw_t,   48, 1536, 48, 0);
    fill(3, m_out_w,   outw_t,  1536, 768, 1536, 0);
    fill(4, ggw,       gates_t, 768, 768, 1536, 0);
    fill(5, gmw,       gates_t, 768, 768, 1536, 768);
    fill(6, ow,        ow_t,    768, 768, 768, 0);
    tcvt7_k<<<t0, tblk, 0, stream>>>(tp);

    // ---- forward ----
    adj_k<<<16, blk, 0, stream>>>(nv1, nv2, out_adj);
    ln_k<<<M_ROWS, blk, 0, stream>>>(x, nullptr, n1w, n1b, nullptr, xn_bf);

    // x_gcn (+ conv over L): 128-tile split-K=6, bf16 partials -> combineb
    gemm_k<128, 128><<<dim3(32, 6, 6), blk, 0, stream>>>(
        xn_bf, DM, wcat_t, nullptr, nullptr, nullptr, nullptr, 0,
        DM, 8 * DM, FLAG_CONV | FLAG_PB16, 16, P1b, zpage, nullptr);
    combineb_k<<<(M_ROWS * DM + 255) / 256, blk, 0, stream>>>(
        P1b, 6, DM, conv_b, gcn_b, nullptr, gcnmam, 2 * DM, 0, nullptr);
    // xz = xn @ m_in_w -> bf16 [4096][3072]  (128-tile, 768 blocks)
    gemm_k<128, 128><<<dim3(32, 24, 1), blk, 0, stream>>>(
        xn_bf, DM, in_w_t, nullptr, nullptr, nullptr, xz_bf, 2 * DI,
        2 * DI, DM, 0, 1 << 20, nullptr, zpage, nullptr);
    // xm = silu(dwconv(xm)) -> xmc bf16
    dwconv_k<<<(M_ROWS * DI + 255) / 256, blk, 0, stream>>>(xz_bf, m_conv_w, m_conv_b, xmc_bf);
    // x_dbl = xm @ m_xproj_w: split-K=4 fp32 -> P2 -> combine -> xdbl bf16
    gemm_k<64, 32><<<dim3(64, 3, 4), blk, 0, stream>>>(
        xmc_bf, DI, xproj_t, nullptr, nullptr, nullptr, nullptr, 0,
        80, DI, 0, 6, P2, zpage, nullptr);
    combine_k<<<(M_ROWS * 80 + 255) / 256, blk, 0, stream>>>(
        P2, 4, 80, nullptr, nullptr, nullptr, xdbl_bf, 80, 0);
    // dt = softplus(x_dbl[:, :48] @ m_dt_w + b) -> fp32
    gemm_k<64, 64><<<dim3(64, 24, 1), blk, 0, stream>>>(
        xdbl_bf, 80, dtw_t, m_dt_b, nullptr, dtb, nullptr, DI,
        DI, DTRANK, FLAG_SP, 1 << 20, nullptr, zpage, nullptr);
    // segmented selective scan -> y bf16 in place over xmc
    scan_a_k<<<dim3(DI / 256, B_SZ, SEG), blk, 0, stream>>>(
        dtb, xmc_bf, xdbl_bf, m_A_log, Aseg, Bseg);
    scan_b_k<<<dim3(DI / 256, B_SZ, SEG), blk, 0, stream>>>(
        dtb, xmc_bf, xdbl_bf, xz_bf, m_A_log, m_D, Aseg, Bseg);
    // x_mamba = y @ m_out_w: 128-tile split-K=4 bf16 partials -> gcnmam[:, 768:]
    gemm_k<128, 128><<<dim3(32, 6, 4), blk, 0, stream>>>(
        xmc_bf, DI, outw_t, nullptr, nullptr, nullptr, nullptr, 0,
        DM, DI, FLAG_PB16, 6, P3b, zpage, nullptr);
    combineb_k<<<(M_ROWS * DM + 255) / 256, blk, 0, stream>>>(
        P3b, 4, DM, nullptr, nullptr, nullptr, gcnmam + DM, 2 * DM, 0, nullptr);
    // gate GEMM: split-K=2 bf16 partials (over dead xmc) -> fused combine
    gemm_k<64, 64><<<dim3(64, 12, 2), blk, 0, stream>>>(
        gcnmam, 2 * DM, gates_t, nullptr, nullptr, nullptr, nullptr, 0,
        DM, 2 * DM, FLAG_PB16, 12, P4b, zpage, nullptr);
    combineb_k<<<(M_ROWS * DM + 255) / 256, blk, 0, stream>>>(
        P4b, 2, DM, ggb, gmb, nullptr, fused, DM, FLAG_FUSE, gcnmam);
    // out = fused @ out_w + ob -> fp32 (dtb free after gate partials consumed... P3b dead, dtb reused)
    gemm_k<64, 64><<<dim3(64, 12, 1), blk, 0, stream>>>(
        fused, DM, ow_t, ob, nullptr, outtmp, nullptr, DM,
        DM, DM, 0, 1 << 20, nullptr, zpage, nullptr);
    // final LN2(outtmp + x) -> fp32 d_out
    ln_k<<<M_ROWS, blk, 0, stream>>>(outtmp, x, n2w, n2b, out_main, nullptr);
}

// Round 12
// 630.303 us; speedup vs baseline: 1.0126x; 1.0126x over previous
//
#include <hip/hip_runtime.h>
#include <math.h>

typedef unsigned short ushort_t;

#define B_SZ 8
#define LSEQ 512
#define DM 768
#define DI 1536
#define DSTATE 16
#define DTRANK 48
#define M_ROWS (B_SZ * LSEQ)   // 4096

#define FLAG_SP   1
#define FLAG_CONV 2
#define FLAG_FUSE 4
#define FLAG_PB16 8

#define SEG 16
#define SL  32

using short8v = __attribute__((ext_vector_type(8))) short;
using float4v = __attribute__((ext_vector_type(4))) float;

#define AS1(p) ((const __attribute__((address_space(1))) void*)(p))
#define AS3(p) ((__attribute__((address_space(3))) void*)(p))

__device__ __forceinline__ float us2f(ushort_t u) {
    union { unsigned int i; float f; } cv; cv.i = ((unsigned int)u) << 16; return cv.f;
}
__device__ __forceinline__ ushort_t f2bs(float f) {
    union { float f; unsigned int u; } cv; cv.f = f;
    unsigned int r = cv.u + 0x7FFFu + ((cv.u >> 16) & 1u);   // RNE
    return (ushort_t)(r >> 16);
}

// ---------------------------------------------------------------------------
// MFMA GEMM with direct global->LDS (width=16) staging.
// ---------------------------------------------------------------------------
template <int TM, int TN>
__global__ __launch_bounds__(256) void gemm_k(
    const ushort_t* __restrict__ A, int lda,
    const ushort_t* __restrict__ Wt,
    const float* __restrict__ b1, const float* __restrict__ b2,
    float* __restrict__ Cf, ushort_t* __restrict__ Cb, int ldc,
    int N, int K, int flags, int ktiles_per_z, void* __restrict__ Part,
    const ushort_t* __restrict__ zpage, const ushort_t* __restrict__ Gm)
{
    constexpr int MF = TM / 32;
    constexpr int NF = TN / 32;
    constexpr int AI = TM / 32;
    constexpr int BI = TN / 32;
    __shared__ short Alds[8 * TM * 8];
    __shared__ short Blds[8 * TN * 8];

    const int tid  = threadIdx.x;
    const int wave = tid >> 6;
    const int lane = tid & 63;
    const int l16  = lane & 15;
    const int quad = lane >> 4;
    const int bm   = blockIdx.x * TM;
    const int bn   = blockIdx.y * TN;
    const int wm   = (wave & 1) * (TM / 2);
    const int wn   = (wave >> 1) * (TN / 2);

    float4v acc[MF][NF];
    #pragma unroll
    for (int i = 0; i < MF; i++)
        #pragma unroll
        for (int j = 0; j < NF; j++)
            acc[i][j] = (float4v){0.f, 0.f, 0.f, 0.f};

    const int nkt = (K + 63) >> 6;
    const int kt0 = blockIdx.z * ktiles_per_z;
    const int kt1 = min(nkt, kt0 + ktiles_per_z);
    for (int kt = kt0; kt < kt1; ++kt) {
        const int k0 = kt << 6;
        int koff = k0, sh = 0;
        if (flags & FLAG_CONV) {
            const int seg = kt / 12;
            koff = (kt - seg * 12) << 6;
            sh = (seg < 7) ? (seg - 3) : 0;
        }
        #pragma unroll
        for (int i = 0; i < AI; i++) {
            const int j = wave * AI + i;
            const int slot = j * 64 + lane;
            const int c = slot / TM, r = slot % TM;
            const int mg = bm + r;
            const ushort_t* gp = zpage;
            if (flags & FLAG_CONV) {
                const int ls = (mg & 511) + sh;
                if (ls >= 0 && ls < LSEQ)
                    gp = A + (size_t)((mg >> 9) * LSEQ + ls) * lda + koff + c * 8;
            } else {
                if (k0 + c * 8 < K)
                    gp = A + (size_t)mg * lda + k0 + c * 8;
            }
            __builtin_amdgcn_global_load_lds(AS1(gp), AS3(Alds + j * 512), 16, 0, 0);
        }
        #pragma unroll
        for (int i = 0; i < BI; i++) {
            const int j = wave * BI + i;
            const int slot = j * 64 + lane;
            const int c = slot / TN, r = slot % TN;
            const int ng = bn + r;
            const ushort_t* gp = zpage;
            if (ng < N && (k0 + c * 8) < K)
                gp = Wt + (size_t)ng * K + k0 + c * 8;
            __builtin_amdgcn_global_load_lds(AS1(gp), AS3(Blds + j * 512), 16, 0, 0);
        }
        __syncthreads();

        short8v a0[MF], a1[MF], b0[NF], b1v[NF];
        #pragma unroll
        for (int mi = 0; mi < MF; mi++) {
            const int ar = wm + mi * 16 + l16;
            a0[mi] = *(const short8v*)(Alds + ((size_t)quad * TM + ar) * 8);
            a1[mi] = *(const short8v*)(Alds + ((size_t)(4 + quad) * TM + ar) * 8);
        }
        #pragma unroll
        for (int ni = 0; ni < NF; ni++) {
            const int br = wn + ni * 16 + l16;
            b0[ni] = *(const short8v*)(Blds + ((size_t)quad * TN + br) * 8);
            b1v[ni] = *(const short8v*)(Blds + ((size_t)(4 + quad) * TN + br) * 8);
        }
        #pragma unroll
        for (int mi = 0; mi < MF; mi++)
            #pragma unroll
            for (int ni = 0; ni < NF; ni++) {
                acc[mi][ni] = __builtin_amdgcn_mfma_f32_16x16x32_bf16(
                    a0[mi], b0[ni], acc[mi][ni], 0, 0, 0);
                acc[mi][ni] = __builtin_amdgcn_mfma_f32_16x16x32_bf16(
                    a1[mi], b1v[ni], acc[mi][ni], 0, 0, 0);
            }
        __syncthreads();
    }

    if (Part) {
        const size_t zoff = (size_t)blockIdx.z * M_ROWS * N;
        #pragma unroll
        for (int ni = 0; ni < NF; ni++) {
            const int col = bn + wn + ni * 16 + l16;
            if (col >= N) continue;
            #pragma unroll
            for (int mi = 0; mi < MF; mi++) {
                const int row0 = bm + wm + mi * 16 + quad * 4;
                #pragma unroll
                for (int r = 0; r < 4; r++) {
                    const size_t idx = zoff + (size_t)(row0 + r) * N + col;
                    if (flags & FLAG_PB16)
                        ((ushort_t*)Part)[idx] = f2bs(acc[mi][ni][r]);
                    else
                        ((float*)Part)[idx] = acc[mi][ni][r];
                }
            }
        }
        return;
    }

    #pragma unroll
    for (int ni = 0; ni < NF; ni++) {
        const int col = bn + wn + ni * 16 + l16;
        if (col >= N) continue;
        const float bias = (b1 ? b1[col] : 0.f) + (b2 ? b2[col] : 0.f);
        #pragma unroll
        for (int mi = 0; mi < MF; mi++) {
            const int row0 = bm + wm + mi * 16 + quad * 4;
            #pragma unroll
            for (int r = 0; r < 4; r++) {
                float v = acc[mi][ni][r] + bias;
                const int row = row0 + r;
                if (flags & FLAG_FUSE) {
                    const float g = 1.f / (1.f + __expf(-v));
                    const float xg = us2f(Gm[(size_t)row * (2 * DM) + col]);
                    const float xm = us2f(Gm[(size_t)row * (2 * DM) + DM + col]);
                    Cb[(size_t)row * ldc + col] = f2bs(g * xg + (1.f - g) * xm);
                    continue;
                }
                if (flags & FLAG_SP) v = (v > 20.f) ? v : log1pf(__expf(v));
                const size_t idx = (size_t)row * ldc + col;
                if (Cf) Cf[idx] = v;
                else    Cb[idx] = f2bs(v);
            }
        }
    }
}

// reduce fp32 split-K partials + bias (+softplus)
__global__ void combine_k(const float* __restrict__ Part, int nsplit, int N,
                          const float* __restrict__ b1, const float* __restrict__ b2,
                          float* __restrict__ Cf, ushort_t* __restrict__ Cb,
                          int ldc, int flags)
{
    int t = blockIdx.x * 256 + threadIdx.x;
    if (t >= M_ROWS * N) return;
    const int row = t / N, col = t - row * N;
    float v = 0.f;
    for (int s = 0; s < nsplit; s++) v += Part[(size_t)s * M_ROWS * N + t];
    if (b1) v += b1[col];
    if (b2) v += b2[col];
    if (flags & FLAG_SP) v = (v > 20.f) ? v : log1pf(__expf(v));
    const size_t idx = (size_t)row * ldc + col;
    if (Cf) Cf[idx] = v;
    else    Cb[idx] = f2bs(v);
}

// reduce bf16 split-K partials + bias
__global__ void combineb_k(const ushort_t* __restrict__ Part, int nsplit, int N,
                           const float* __restrict__ b1, const float* __restrict__ b2,
                           float* __restrict__ Cf, ushort_t* __restrict__ Cb,
                           int ldc, int flags)
{
    int t = blockIdx.x * 256 + threadIdx.x;
    if (t >= M_ROWS * N) return;
    const int row = t / N, col = t - row * N;
    float v = 0.f;
    for (int s = 0; s < nsplit; s++) v += us2f(Part[(size_t)s * M_ROWS * N + t]);
    if (b1) v += b1[col];
    if (b2) v += b2[col];
    if (flags & FLAG_SP) v = (v > 20.f) ? v : log1pf(__expf(v));
    const size_t idx = (size_t)row * ldc + col;
    if (Cf) Cf[idx] = v;
    else    Cb[idx] = f2bs(v);
}

// adj = sigmoid(nv1 @ nv2) * (1 - eye)  -> fp32
__global__ void adj_k(const float* __restrict__ nv1, const float* __restrict__ nv2,
                      float* __restrict__ out)
{
    int t = blockIdx.x * 256 + threadIdx.x;
    if (t >= 64 * 64) return;
    int i = t >> 6, j = t & 63;
    float s = 0.f;
    #pragma unroll
    for (int k = 0; k < 16; k++) s += nv1[i * 16 + k] * nv2[k * 64 + j];
    out[t] = (i == j) ? 0.f : 1.f / (1.f + __expf(-s));
}

// LayerNorm over last dim (768)
__global__ __launch_bounds__(256) void ln_k(
    const float* __restrict__ xin, const float* __restrict__ addf,
    const float* __restrict__ w, const float* __restrict__ bparam,
    float* __restrict__ outf, ushort_t* __restrict__ outb)
{
    const int r = blockIdx.x;
    const int tid = threadIdx.x;
    const size_t base = (size_t)r * DM;
    float v[3];
    float s = 0.f, ss = 0.f;
    #pragma unroll
    for (int j = 0; j < 3; j++) {
        const int c = tid + 256 * j;
        float vv = xin[base + c];
        if (addf) vv += addf[base + c];
        v[j] = vv; s += vv; ss += vv * vv;
    }
    #pragma unroll
    for (int o = 32; o > 0; o >>= 1) { s += __shfl_down(s, o); ss += __shfl_down(ss, o); }
    __shared__ float sw[4], ssw[4];
    __shared__ float mu_s, rs_s;
    const int wid = tid >> 6;
    if ((tid & 63) == 0) { sw[wid] = s; ssw[wid] = ss; }
    __syncthreads();
    if (tid == 0) {
        float st = 0.f, sst = 0.f;
        #pragma unroll
        for (int i = 0; i < 4; i++) { st += sw[i]; sst += ssw[i]; }
        const float mu = st / (float)DM;
        const float var = sst / (float)DM - mu * mu;
        mu_s = mu; rs_s = rsqrtf(fmaxf(var, 0.f) + 1e-5f);
    }
    __syncthreads();
    const float mu = mu_s, rs = rs_s;
    #pragma unroll
    for (int j = 0; j < 3; j++) {
        const int c = tid + 256 * j;
        const float o = (v[j] - mu) * rs * w[c] + bparam[c];
        if (outf) outf[base + c] = o;
        if (outb) outb[base + c] = f2bs(o);
    }
}

// batched tiled transpose+cvt: 7 descriptors, flat tile index
struct TDesc { const float* in; ushort_t* out; int R, C, ldout, off, tile0; };
struct TPack { TDesc d[7]; };
__global__ void tcvt7_k(TPack p)
{
    __shared__ float tile[32][33];
    int di = 0;
    #pragma unroll
    for (int i = 1; i < 7; i++) if (blockIdx.x >= p.d[i].tile0) di = i;
    const TDesc dd = p.d[di];
    const int lt = blockIdx.x - dd.tile0;
    const int tilesX = (dd.C + 31) >> 5;
    const int c0 = (lt % tilesX) * 32, r0 = (lt / tilesX) * 32;
    const int tx = threadIdx.x, ty = threadIdx.y;   // (32, 8)
    #pragma unroll
    for (int j = 0; j < 4; j++) {
        const int rr = r0 + ty + j * 8;
        if (rr < dd.R && c0 + tx < dd.C)
            tile[ty + j * 8][tx] = dd.in[(size_t)rr * dd.C + c0 + tx];
    }
    __syncthreads();
    #pragma unroll
    for (int j = 0; j < 4; j++) {
        const int cc = c0 + ty + j * 8;
        const int kk = r0 + tx;
        if (cc < dd.C && kk < dd.R)
            dd.out[(size_t)cc * dd.ldout + dd.off + kk] = f2bs(tile[tx][ty + j * 8]);
    }
}

// wcat_t[768][6144]
__global__ void wcat_k(const float* __restrict__ cw, const float* __restrict__ gw,
                       ushort_t* __restrict__ out)
{
    int t = blockIdx.x * 256 + threadIdx.x;
    if (t >= DM * 8 * DM) return;
    const int o = t / (8 * DM);
    const int rr = t - o * 8 * DM;
    const int seg = rr / DM;
    const int i = rr - seg * DM;
    float v = (seg < 7) ? cw[(size_t)o * (DM * 7) + i * 7 + seg]
                        : gw[(size_t)i * DM + o];
    out[t] = f2bs(v);
}

// depthwise causal conv + bias + silu
__global__ void dwconv_k(const ushort_t* __restrict__ xz, const float* __restrict__ w,
                         const float* __restrict__ bcv, ushort_t* __restrict__ out)
{
    int t = blockIdx.x * 256 + threadIdx.x;
    if (t >= M_ROWS * DI) return;
    const int d = t % DI;
    const int bl = t / DI;
    const int l = bl & 511;
    const ushort_t* xp = xz + (size_t)bl * (2 * DI) + d;
    float s = bcv[d];
    #pragma unroll
    for (int k = 0; k < 4; k++) {
        const int ls = l + k - 3;
        if (ls >= 0) s += w[d * 4 + k] * us2f(xp[(ptrdiff_t)(k - 3) * (2 * DI)]);
    }
    out[t] = f2bs(s / (1.f + __expf(-s)));
}

// ---------------------------------------------------------------------------
// Segmented selective scan with INLINE dt (softplus(xdbl[:, :48]@dtw + b)).
// Thread = one d; xdbl dt-columns staged in LDS (broadcast); dtw in registers.
// ---------------------------------------------------------------------------
__global__ __launch_bounds__(256) void scan_a_k(
    const ushort_t* __restrict__ xmc,
    const ushort_t* __restrict__ xdbl, const float* __restrict__ A_log,
    const ushort_t* __restrict__ dtw, const float* __restrict__ dtbias,
    ushort_t* __restrict__ Aseg, float* __restrict__ Bseg)
{
    __shared__ ushort_t B_s[SL][16];
    __shared__ ushort_t xd_s[SL][DTRANK];
    const int tid = threadIdx.x;
    const int d   = blockIdx.x * 256 + tid;
    const int b   = blockIdx.y;
    const int sg  = blockIdx.z;
    const int l0  = sg * SL;

    const ushort_t* dbp = xdbl + ((size_t)b * LSEQ + l0) * 80;
    #pragma unroll
    for (int e = 0; e < 2; e++) {
        const int idx = tid + e * 256;
        const int ll = idx >> 4, n = idx & 15;
        B_s[ll][n] = dbp[(size_t)ll * 80 + DTRANK + n];
    }
    #pragma unroll
    for (int e = 0; e < 6; e++) {
        const int idx = tid + e * 256;
        const int ll = idx / DTRANK, kk = idx - ll * DTRANK;
        xd_s[ll][kk] = dbp[(size_t)ll * 80 + kk];
    }

    float wreg[DTRANK];
    #pragma unroll
    for (int k = 0; k < DTRANK; k++) wreg[k] = us2f(dtw[(size_t)d * DTRANK + k]);
    const float bias = dtbias[d];

    float Ad[16], h[16], Ap[16];
    #pragma unroll
    for (int n = 0; n < 16; n++) {
        Ad[n] = -__expf(A_log[(size_t)d * DSTATE + n]);
        h[n] = 0.f; Ap[n] = 1.f;
    }
    const ushort_t* xp = xmc + ((size_t)b * LSEQ + l0) * DI + d;
    __syncthreads();

    for (int l = 0; l < SL; ++l) {
        float dv = bias;
        #pragma unroll
        for (int k = 0; k < DTRANK; k++) dv += us2f(xd_s[l][k]) * wreg[k];
        const float dtv = (dv > 20.f) ? dv : log1pf(__expf(dv));
        const float dx  = dtv * us2f(xp[(size_t)l * DI]);
        #pragma unroll
        for (int n = 0; n < 16; n++) {
            const float a = __expf(dtv * Ad[n]);
            h[n] = a * h[n] + us2f(B_s[l][n]) * dx;
            Ap[n] *= a;
        }
    }
    #pragma unroll
    for (int n = 0; n < 16; n++) {
        const size_t o = ((size_t)(b * SEG + sg) * 16 + n) * DI + d;
        Aseg[o] = f2bs(Ap[n]);
        Bseg[o] = h[n];
    }
}

__global__ __launch_bounds__(256) void scan_b_k(
    ushort_t* __restrict__ xmc,
    const ushort_t* __restrict__ xdbl, const ushort_t* __restrict__ xz,
    const float* __restrict__ A_log, const float* __restrict__ Dp,
    const ushort_t* __restrict__ dtw, const float* __restrict__ dtbias,
    const ushort_t* __restrict__ Aseg, const float* __restrict__ Bseg)
{
    __shared__ ushort_t B_s[SL][16];
    __shared__ ushort_t C_s[SL][16];
    __shared__ ushort_t xd_s[SL][DTRANK];
    const int tid = threadIdx.x;
    const int d   = blockIdx.x * 256 + tid;
    const int b   = blockIdx.y;
    const int sg  = blockIdx.z;
    const int l0  = sg * SL;

    const ushort_t* dbp = xdbl + ((size_t)b * LSEQ + l0) * 80;
    #pragma unroll
    for (int e = 0; e < 2; e++) {
        const int idx = tid + e * 256;
        const int ll = idx >> 4, n = idx & 15;
        B_s[ll][n] = dbp[(size_t)ll * 80 + DTRANK + n];
        C_s[ll][n] = dbp[(size_t)ll * 80 + DTRANK + DSTATE + n];
    }
    #pragma unroll
    for (int e = 0; e < 6; e++) {
        const int idx = tid + e * 256;
        const int ll = idx / DTRANK, kk = idx - ll * DTRANK;
        xd_s[ll][kk] = dbp[(size_t)ll * 80 + kk];
    }

    float wreg[DTRANK];
    #pragma unroll
    for (int k = 0; k < DTRANK; k++) wreg[k] = us2f(dtw[(size_t)d * DTRANK + k]);
    const float bias = dtbias[d];

    float Ad[16], h[16];
    #pragma unroll
    for (int n = 0; n < 16; n++) {
        Ad[n] = -__expf(A_log[(size_t)d * DSTATE + n]);
        h[n] = 0.f;
    }
    for (int s = 0; s < sg; ++s) {
        #pragma unroll
        for (int n = 0; n < 16; n++) {
            const size_t o = ((size_t)(b * SEG + s) * 16 + n) * DI + d;
            h[n] = us2f(Aseg[o]) * h[n] + Bseg[o];
        }
    }
    const float Dd = Dp[d];
    ushort_t*       xp = xmc + ((size_t)b * LSEQ + l0) * DI + d;
    const ushort_t* zp = xz  + ((size_t)b * LSEQ + l0) * (2 * DI) + DI + d;
    __syncthreads();

    for (int l = 0; l < SL; ++l) {
        float dv = bias;
        #pragma unroll
        for (int k = 0; k < DTRANK; k++) dv += us2f(xd_s[l][k]) * wreg[k];
        const float dtv = (dv > 20.f) ? dv : log1pf(__expf(dv));
        const float xv  = us2f(xp[(size_t)l * DI]);
        const float dx  = dtv * xv;
        float p = 0.f;
        #pragma unroll
        for (int n = 0; n < 16; n++) {
            const float a = __expf(dtv * Ad[n]);
            h[n] = a * h[n] + us2f(B_s[l][n]) * dx;
            p += h[n] * us2f(C_s[l][n]);
        }
        const float zv = us2f(zp[(size_t)l * 2 * DI]);
        const float sz = zv / (1.f + __expf(-zv));
        xp[(size_t)l * DI] = f2bs((p + Dd * xv) * sz);
    }
}

extern "C" void kernel_launch(void* const* d_in, const int* in_sizes, int n_in,
                              void* d_out, int out_size, void* d_ws, size_t ws_size,
                              hipStream_t stream)
{
    const float* x        = (const float*)d_in[0];
    const float* nv1      = (const float*)d_in[1];
    const float* nv2      = (const float*)d_in[2];
    const float* n1w      = (const float*)d_in[3];
    const float* n1b      = (const float*)d_in[4];
    const float* n2w      = (const float*)d_in[5];
    const float* n2b      = (const float*)d_in[6];
    const float* gcn_w    = (const float*)d_in[7];
    const float* gcn_b    = (const float*)d_in[8];
    const float* conv_w   = (const float*)d_in[9];
    const float* conv_b   = (const float*)d_in[10];
    const float* ggw      = (const float*)d_in[11];
    const float* ggb      = (const float*)d_in[12];
    const float* gmw      = (const float*)d_in[13];
    const float* gmb      = (const float*)d_in[14];
    const float* ow       = (const float*)d_in[15];
    const float* ob       = (const float*)d_in[16];
    const float* m_in_w   = (const float*)d_in[17];
    const float* m_conv_w = (const float*)d_in[18];
    const float* m_conv_b = (const float*)d_in[19];
    const float* m_xproj_w= (const float*)d_in[20];
    const float* m_dt_w   = (const float*)d_in[21];
    const float* m_dt_b   = (const float*)d_in[22];
    const float* m_A_log  = (const float*)d_in[23];
    const float* m_D      = (const float*)d_in[24];
    const float* m_out_w  = (const float*)d_in[25];

    float* out_main = (float*)d_out;
    float* out_adj  = out_main + (size_t)M_ROWS * DM;

    // workspace layout (~98.1 MB incl. zero page)
    ushort_t* wsb = (ushort_t*)d_ws;
    ushort_t* xn_bf   = wsb;                       //  3,145,728
    ushort_t* xz_bf   = xn_bf   + 3145728;         // 12,582,912
    ushort_t* xmc_bf  = xz_bf   + 12582912;        //  6,291,456 (y in place)
    ushort_t* xdbl_bf = xmc_bf  + 6291456;         //    327,680
    ushort_t* gcnmam  = xdbl_bf + 327680;          //  6,291,456 [xgcn|xmamba]
    ushort_t* wcat_t  = gcnmam  + 6291456;         //  4,718,592
    ushort_t* in_w_t  = wcat_t  + 4718592;         //  2,359,296
    ushort_t* xproj_t = in_w_t  + 2359296;         //    122,880
    ushort_t* dtw_t   = xproj_t + 122880;          //     73,728
    ushort_t* outw_t  = dtw_t   + 73728;           //  1,179,648
    ushort_t* gates_t = outw_t  + 1179648;         //  1,179,648
    ushort_t* ow_t    = gates_t + 1179648;         //    589,824
    float*    dtb     = (float*)(ow_t + 589824);   //  6,291,456 fp32 (scratch)
    ushort_t* zpage   = (ushort_t*)(dtb + 6291456);//  256 B zeroed
    // aliases
    ushort_t* fused   = xz_bf + 3145728;           // xz dead after scan
    float*    outtmp  = dtb;                       // scratch
    ushort_t* P1b     = xz_bf;                     // conv bf16 partials (xz+xmc, dead pre-in_proj)
    float*    P2      = (float*)wcat_t;            // xproj fp32 partials (wcat dead)
    ushort_t* P3b     = (ushort_t*)dtb;            // out_proj bf16 partials
    ushort_t* Aseg    = xn_bf;                     // xn dead after in_proj
    float*    Bseg    = (float*)wcat_t;            // wcat+in_w dead after GEMMs

    const dim3 blk(256);
    const dim3 tblk(32, 8);

    hipMemsetAsync(zpage, 0, 256, stream);

    // ---- weight prep ----
    wcat_k<<<(DM * 8 * DM + 255) / 256, blk, 0, stream>>>(conv_w, gcn_w, wcat_t);
    TPack tp;
    int t0 = 0;
    auto fill = [&](int i, const float* in, ushort_t* out, int R, int C, int ldo, int off) {
        tp.d[i] = TDesc{in, out, R, C, ldo, off, t0};
        t0 += ((C + 31) / 32) * ((R + 31) / 32);
    };
    fill(0, m_in_w,    in_w_t,  768, 3072, 768, 0);
    fill(1, m_xproj_w, xproj_t, 1536, 80, 1536, 0);
    fill(2, m_dt_w,    dtw_t,   48, 1536, 48, 0);
    fill(3, m_out_w,   outw_t,  1536, 768, 1536, 0);
    fill(4, ggw,       gates_t, 768, 768, 1536, 0);
    fill(5, gmw,       gates_t, 768, 768, 1536, 768);
    fill(6, ow,        ow_t,    768, 768, 768, 0);
    tcvt7_k<<<t0, tblk, 0, stream>>>(tp);

    // ---- forward ----
    adj_k<<<16, blk, 0, stream>>>(nv1, nv2, out_adj);
    ln_k<<<M_ROWS, blk, 0, stream>>>(x, nullptr, n1w, n1b, nullptr, xn_bf);

    // x_gcn (+ conv over L): 128-tile split-K=6, bf16 partials -> combineb
    gemm_k<128, 128><<<dim3(32, 6, 6), blk, 0, stream>>>(
        xn_bf, DM, wcat_t, nullptr, nullptr, nullptr, nullptr, 0,
        DM, 8 * DM, FLAG_CONV | FLAG_PB16, 16, P1b, zpage, nullptr);
    combineb_k<<<(M_ROWS * DM + 255) / 256, blk, 0, stream>>>(
        P1b, 6, DM, conv_b, gcn_b, nullptr, gcnmam, 2 * DM, 0);
    // xz = xn @ m_in_w -> bf16 [4096][3072]  (128-tile, 768 blocks)
    gemm_k<128, 128><<<dim3(32, 24, 1), blk, 0, stream>>>(
        xn_bf, DM, in_w_t, nullptr, nullptr, nullptr, xz_bf, 2 * DI,
        2 * DI, DM, 0, 1 << 20, nullptr, zpage, nullptr);
    // xm = silu(dwconv(xm)) -> xmc bf16
    dwconv_k<<<(M_ROWS * DI + 255) / 256, blk, 0, stream>>>(xz_bf, m_conv_w, m_conv_b, xmc_bf);
    // x_dbl = xm @ m_xproj_w: split-K=4 fp32 -> P2 -> combine -> xdbl bf16
    gemm_k<64, 32><<<dim3(64, 3, 4), blk, 0, stream>>>(
        xmc_bf, DI, xproj_t, nullptr, nullptr, nullptr, nullptr, 0,
        80, DI, 0, 6, P2, zpage, nullptr);
    combine_k<<<(M_ROWS * 80 + 255) / 256, blk, 0, stream>>>(
        P2, 4, 80, nullptr, nullptr, nullptr, xdbl_bf, 80, 0);
    // segmented selective scan (dt computed inline) -> y bf16 in place over xmc
    scan_a_k<<<dim3(DI / 256, B_SZ, SEG), blk, 0, stream>>>(
        xmc_bf, xdbl_bf, m_A_log, dtw_t, m_dt_b, Aseg, Bseg);
    scan_b_k<<<dim3(DI / 256, B_SZ, SEG), blk, 0, stream>>>(
        xmc_bf, xdbl_bf, xz_bf, m_A_log, m_D, dtw_t, m_dt_b, Aseg, Bseg);
    // x_mamba = y @ m_out_w: 128-tile split-K=4 bf16 partials -> gcnmam[:, 768:]
    gemm_k<128, 128><<<dim3(32, 6, 4), blk, 0, stream>>>(
        xmc_bf, DI, outw_t, nullptr, nullptr, nullptr, nullptr, 0,
        DM, DI, FLAG_PB16, 6, P3b, zpage, nullptr);
    combineb_k<<<(M_ROWS * DM + 255) / 256, blk, 0, stream>>>(
        P3b, 4, DM, nullptr, nullptr, nullptr, gcnmam + DM, 2 * DM, 0);
    // gate GEMM + fused sigmoid blend epilogue -> fused bf16 (over dead xz)
    gemm_k<64, 64><<<dim3(64, 12, 1), blk, 0, stream>>>(
        gcnmam, 2 * DM, gates_t, ggb, gmb, nullptr, fused, DM,
        DM, 2 * DM, FLAG_FUSE, 1 << 20, nullptr, zpage, gcnmam);
    // out = fused @ out_w + ob -> fp32 (dtb scratch free again)
    gemm_k<64, 64><<<dim3(64, 12, 1), blk, 0, stream>>>(
        fused, DM, ow_t, ob, nullptr, outtmp, nullptr, DM,
        DM, DM, 0, 1 << 20, nullptr, zpage, nullptr);
    // final LN2(outtmp + x) -> fp32 d_out
    ln_k<<<M_ROWS, blk, 0, stream>>>(outtmp, x, n2w, n2b, out_main, nullptr);
}